// Round 9
// baseline (673.180 us; speedup 1.0000x reference)
//
#include <hip/hip_runtime.h>
#include <math.h>

#define BB 64
#define TT 1024
#define KK 128
#define START_TAG 126
#define STOP_TAG 127
#define NTH 128      // 2 waves; lane tid owns row j = tid (full 128-wide dot in-lane)
#define CS 32        // timesteps of raw feats staged per chunk (16 KB LDS x2)

typedef float v4f __attribute__((ext_vector_type(4)));

// Raw workgroup barrier WITHOUT the vmcnt(0) drain __syncthreads performs.
__device__ __forceinline__ void step_barrier() {
  asm volatile("s_waitcnt lgkmcnt(0)" ::: "memory");  // own LDS writes visible
  __builtin_amdgcn_s_barrier();
  asm volatile("" ::: "memory");                      // no hoisting reads above
}

__device__ __forceinline__ float vmax4(v4f v) {
  return fmaxf(fmaxf(v[0], v[1]), fmaxf(v[2], v[3]));
}
__device__ __forceinline__ v4f exp4(v4f v, float m) {
  v4f o;
  o[0] = __expf(v[0] - m); o[1] = __expf(v[1] - m);
  o[2] = __expf(v[2] - m); o[3] = __expf(v[3] - m);
  return o;
}

// Forward algorithm, log/exp-free inner chain, lag-1 normalization.
// Lane tid owns row j=tid: E_row = exp(T[j][:] - maxT_j) held in 32 NAMED v4f
// locals (NOT an array: hipcc leaves unrolled-indexed local arrays in scratch —
// rounds 2/7 showed VGPR=160/88 + 1MB scratch writeback; named SSA values
// must be register-allocated, and __launch_bounds__(128,1) grants 512 VGPRs).
// Per step (one barrier, no cross-lane reduce):
//   e broadcast: 32 uniform-address ds_read_b128 (conflict-free broadcast)
//   d_j = dot(E_row, e)                 (64 pk_fma in-lane -> full dot)
//   e'_j = d_j * exp(feat[t][j]+maxT_j) * rcp(s_prev)   (off-chain factors)
//   s' = d_START (lane 126: START row of E is all-ones => d = sum_k e_k)
//   all-gather: one ds_write_b32 per lane (conflict-free), raw barrier.
__global__ __launch_bounds__(NTH, 1) void crf_forward(
    const float* __restrict__ feats,   // [B,T,K]
    const int*   __restrict__ tags,    // [B,T]
    const int*   __restrict__ lens,    // [B]
    const float* __restrict__ trans,   // [K,K]
    float*       __restrict__ out_pb)  // [B]: forward_score - gold_score
{
  __shared__ __align__(16) float ebuf[2][KK];       // double-buffered e
  __shared__ float sbuf[2];                         // double-buffered divisor
  __shared__ __align__(16) float Fraw[2][CS * KK];  // 2 x 16 KB raw feats
  __shared__ float wsum[2];

  const int tid = threadIdx.x;                      // 0..127 == owned row
  const int b   = blockIdx.x;
  const int L   = lens[b];
  const float* fb = feats + (size_t)b * TT * KK;

  // ---- E row in 32 named v4f registers: load+max, then exp in place ----
#define EGRPS(X) X(0) X(1) X(2) X(3) X(4) X(5) X(6) X(7)
#define DECLG(g) v4f E##g##0, E##g##1, E##g##2, E##g##3;
  EGRPS(DECLG)
  float mT = -INFINITY;
  {
    const v4f* tr = (const v4f*)(trans + (size_t)tid * KK);
#define LOADG(g)                                                        \
    E##g##0 = tr[4*g+0]; E##g##1 = tr[4*g+1];                           \
    E##g##2 = tr[4*g+2]; E##g##3 = tr[4*g+3];                           \
    mT = fmaxf(mT, fmaxf(fmaxf(vmax4(E##g##0), vmax4(E##g##1)),         \
                         fmaxf(vmax4(E##g##2), vmax4(E##g##3))));
    EGRPS(LOADG)
#define EXPG(g)                                                         \
    E##g##0 = exp4(E##g##0, mT); E##g##1 = exp4(E##g##1, mT);           \
    E##g##2 = exp4(E##g##2, mT); E##g##3 = exp4(E##g##3, mT);
    EGRPS(EXPG)
  }

  // ---- init: e0 = onehot(START), s0 = 1, M0 = feats[b,0,START] ----
  float ev = (tid == START_TAG) ? 1.0f : 0.0f;      // lane's own e_j
  ebuf[0][tid] = ev;
  if (tid == 0) sbuf[0] = 1.0f;
  float M = fb[START_TAG];                          // uniform across lanes

  // ---- prefetch chunk 0 raw feats into registers (8 x float4, coalesced) ----
  float4 pf[8];
  {
    const float4* s4 = (const float4*)fb;
    #pragma unroll
    for (int i = 0; i < 8; ++i) pf[i] = s4[i * NTH + tid];
  }

  // ---- chunked main recurrence ----
  int p = 0;
  for (int c = 0; c * CS < L; ++c) {
    // stage current chunk regs -> LDS (vmcnt wait lands here; pf loads were
    // issued a full chunk ago, so the wait is ~free after c=0)
    float4* Fb4 = (float4*)Fraw[c & 1];
    #pragma unroll
    for (int i = 0; i < 8; ++i) Fb4[i * NTH + tid] = pf[i];
    // issue prefetch for chunk c+1; stays outstanding across step barriers
    if ((c + 1) * CS < L) {
      const float4* s4 = (const float4*)(fb + (size_t)(c + 1) * CS * KK);
      #pragma unroll
      for (int i = 0; i < 8; ++i) pf[i] = s4[i * NTH + tid];
    }
    step_barrier();                                 // Fraw (+init at c=0) visible

    const float* Fc = Fraw[c & 1];
    const int t_end = (L < (c + 1) * CS) ? L : (c + 1) * CS;
    for (int t = (c == 0) ? 1 : c * CS; t < t_end; ++t) {
      // off-chain factors first: stale divisor + raw feat
      const float sp = sbuf[p];
      const float Fr = Fc[(t & (CS - 1)) * KK + tid];
      float rr; asm("v_rcp_f32 %0, %1" : "=v"(rr) : "v"(sp));
      const float rF = __expf(Fr + mT) * rr;

      // full matvec: 32 uniform broadcast b128 reads, 64 pk_fma in-lane
      const v4f* eb = (const v4f*)ebuf[p];
      v4f a0 = {0.f,0.f,0.f,0.f}, a1 = a0, a2 = a0, a3 = a0;
#define DOTG(g)                                                         \
      a0 += eb[4*g+0] * E##g##0;                                        \
      a1 += eb[4*g+1] * E##g##1;                                        \
      a2 += eb[4*g+2] * E##g##2;                                        \
      a3 += eb[4*g+3] * E##g##3;
      EGRPS(DOTG)
      v4f av = (a0 + a1) + (a2 + a3);
      const float d = (av[0] + av[1]) + (av[2] + av[3]);

      ev = d * rF;
      ebuf[p ^ 1][tid] = ev;                        // conflict-free all-gather
      if (tid == START_TAG) sbuf[p ^ 1] = d;        // d_START = sum_k e_k
      M += __logf(sp);                              // off-chain, uniform
      p ^= 1;
      step_barrier();
    }
  }

  // ---- terminal: fwd = M + log(sum_j e_j) ----
  float sm = ev;
  #pragma unroll
  for (int m = 1; m < 64; m <<= 1) sm += __shfl_xor(sm, m, 64);
  if ((tid & 63) == 0) wsum[tid >> 6] = sm;
  step_barrier();
  const float fwd = M + __logf(wsum[0] + wsum[1]);
  step_barrier();                                   // protect wsum reuse

  // ---- gold score (trans/feats L2-hot; independent gathers) ----
  float g = 0.f;
  const int* tg = tags + b * TT;
  for (int t = tid; t < TT; t += NTH) {
    if (t < L)     g += fb[(size_t)t * KK + tg[t]];
    if (t < L - 1) g += trans[(size_t)tg[t + 1] * KK + tg[t]];
  }
  #pragma unroll
  for (int m = 1; m < 64; m <<= 1) g += __shfl_xor(g, m, 64);
  if ((tid & 63) == 0) wsum[tid >> 6] = g;
  step_barrier();
  if (tid == 0) out_pb[b] = fwd - (wsum[0] + wsum[1]);
}

__global__ void crf_mean(const float* __restrict__ pb, float* __restrict__ out) {
  int tid = threadIdx.x;  // 64 threads, one wave
  float v = pb[tid];
  #pragma unroll
  for (int m = 1; m < 64; m <<= 1) v += __shfl_xor(v, m, 64);
  if (tid == 0) out[0] = v * (1.0f / 64.0f);
}

extern "C" void kernel_launch(void* const* d_in, const int* in_sizes, int n_in,
                              void* d_out, int out_size, void* d_ws, size_t ws_size,
                              hipStream_t stream) {
  const float* feats = (const float*)d_in[0];
  const int*   tags  = (const int*)d_in[1];
  const int*   lens  = (const int*)d_in[2];
  const float* trans = (const float*)d_in[3];
  float* pb = (float*)d_ws;   // 64 floats of scratch
  crf_forward<<<BB, NTH, 0, stream>>>(feats, tags, lens, trans, pb);
  crf_mean<<<1, 64, 0, stream>>>(pb, (float*)d_out);
}